// Round 2
// baseline (4540.075 us; speedup 1.0000x reference)
//
#include <hip/hip_runtime.h>
#include <math.h>

#define NS 56        // B*(T-1) = 4*14 slices
#define NPIX 65536   // 256*256
#define NB_RED 1024

static constexpr double D_PI = 3.14159265358979323846;

// ---------------- workspace layout (float offsets) ----------------
#define OFF_PART 0                      // 2048 doubles = 4096 floats
#define OFF_S    4096
#define OFF_HELM (OFF_S + NPIX)
#define OFF_H    (OFF_HELM + NPIX)
#define OFF_Q0   (OFF_H + NS * NPIX)
#define OFF_Q1   (OFF_Q0 + NS * NPIX)
#define OFF_QB   (OFF_Q1 + NS * NPIX)
#define OFF_TA   (OFF_QB + NS * NPIX)
#define OFF_TB   (OFF_TA + NS * NPIX)
// conv phase reuses the QG region (QG fully consumed by then)
#define OFF_Z1   OFF_H
#define OFF_Z2   (OFF_Z1 + 4 * 64 * NPIX)
#define OFF_BUFC (OFF_Z2 + 4 * 64 * NPIX)
#define OFF_XA   (OFF_BUFC + 4 * 64 * NPIX)

#define QCLAMP 1.0e12f
#define HCLAMP 1.0e15f

// ---------------- init: DST matrix + Helmholtz eigenvalues ----------------
__global__ __launch_bounds__(256) void k_dst_init(float* __restrict__ S,
                                                  float* __restrict__ HM,
                                                  float dx2f) {
  int idx = blockIdx.x * 256 + threadIdx.x;
  int i = idx >> 8, j = idx & 255;
  float sv = 0.f, hv = 1.f;
  if (i < 254 && j < 254) {
    double arg = D_PI * (double)((i + 1) * (j + 1)) / 255.0;
    sv = (float)((2.0 / sqrt(510.0)) * sin(arg));
    double la = 2.0 * (cos(D_PI * (double)(i + 1) / 255.0) - 1.0) / (double)dx2f
              + 2.0 * (cos(D_PI * (double)(j + 1) / 255.0) - 1.0) / (double)dx2f;
    hv = (float)((9.81 / 1e-4) * la - 9.81 * 1e-4 / (2.7 * 2.7));
  }
  S[idx] = sv;
  HM[idx] = hv;
}

// ---------------- QG init: h = x[:, :-1]; q = qb = h2pv(h, h) ----------------
__global__ __launch_bounds__(256) void k_qg_init(const float* __restrict__ x,
                                                 float* __restrict__ h,
                                                 float* __restrict__ q,
                                                 float* __restrict__ qb,
                                                 float dx2, float gf, float gfc) {
  int idx = blockIdx.x * 256 + threadIdx.x;
  int s = idx >> 16, p = idx & 65535;
  int y = p >> 8, xx = p & 255;
  int b = s / 14, t = s - b * 14;
  const float* hb = x + (size_t)(b * 15 + t) * NPIX;
  float hc = hb[p];
  float qv;
  if (y >= 2 && y <= 252 && xx >= 2 && xx <= 252) {
    qv = gf * ((hb[p + 256] + hb[p - 256] - 2.f * hc) / dx2
             + (hb[p + 1] + hb[p - 1] - 2.f * hc) / dx2) - gfc * hc;
  } else {
    qv = -gfc * hc;  // IND12 band
  }
  h[idx] = hc;
  q[idx] = qv;
  qb[idx] = qv;
}

// ---------------- q1 = q + DT*rhs(h2uv(h), q); tA = padded (q1 - qb) ----------------
__global__ __launch_bounds__(256) void k_qrhs(const float* __restrict__ h,
                                              const float* __restrict__ qc,
                                              const float* __restrict__ qb,
                                              float* __restrict__ qn,
                                              float* __restrict__ tA,
                                              float ngf, float pgf, float fdx,
                                              float cc, float dtf) {
  int idx = blockIdx.x * 256 + threadIdx.x;
  int s = idx >> 16, p = idx & 65535;
  int y = p >> 8, xx = p & 255;
  const float* H = h + (size_t)s * NPIX;
  const float* Q = qc + (size_t)s * NPIX;
  float qv = Q[p];
  float q1 = qv;
  if (y >= 2 && y <= 252 && xx >= 2 && xx <= 252) {
    float hSW = H[p + 255], hS = H[p + 256], hSE = H[p + 257];
    float hNW = H[p - 257], hN = H[p - 256], hNE = H[p - 255];
    float hW = H[p - 1], hE = H[p + 1];
    float uA = ngf * (hSW + hS - hN - hNW) / fdx;   // u(y,x)
    float uB = ngf * (hS + hSE - hNE - hN) / fdx;   // u(y,x+1)
    float vA = pgf * (hE + hNE - hNW - hW) / fdx;   // v(y,x)
    float vB = pgf * (hSE + hE - hW - hSW) / fdx;   // v(y+1,x)
    float uT = 0.5f * (uA + uB);
    float vT = 0.5f * (vA + vB);
    float up = fmaxf(uT, 0.f), um = fminf(uT, 0.f);
    float vp = fmaxf(vT, 0.f), vm = fminf(vT, 0.f);
    float Q0 = qv;
    float QE = Q[p + 1], QW = Q[p - 1], QEE = Q[p + 2], QWW = Q[p - 2];
    float QS = Q[p + 256], QN = Q[p - 256], QSS = Q[p + 512], QNN = Q[p - 512];
    float r = -up * cc * (2.f * QE + 3.f * Q0 - 6.f * QW + QWW)
            + um * cc * (QEE - 6.f * QE + 3.f * Q0 + 2.f * QW)
            - vp * cc * (2.f * QS + 3.f * Q0 - 6.f * QN + QNN)
            + vm * cc * (QSS - 6.f * QS + 3.f * Q0 + 2.f * QN);
    q1 = qv + dtf * r;
    // NaN/Inf-proof the unstable dynamics (reference blows up; any finite passes)
    q1 = fminf(fmaxf(q1, -QCLAMP), QCLAMP);
  }
  qn[idx] = q1;
  // bijective remap: interior (y,x in [1,254]) -> (y-1,x-1); boundary -> pad
  // rows/cols 254-255, which MUST be exact zeros for the padded DST GEMM.
  int wy = (y == 0) ? 254 : ((y == 255) ? 255 : y - 1);
  int wx = (xx == 0) ? 254 : ((xx == 255) ? 255 : xx - 1);
  float val = 0.f;
  if (y >= 1 && y <= 254 && xx >= 1 && xx <= 254) val = q1 - qb[idx];
  tA[(size_t)s * NPIX + wy * 256 + wx] = val;
}

// ---------------- batched 256^3 fp32 GEMM: C = A @ B ----------------
// EPI 0: store C. EPI 1: store C / helm. EPI 2: h[interior] = clamp(C + hb)
template <int EPI>
__global__ __launch_bounds__(256) void k_gemm(const float* __restrict__ Ab, int sA,
                                              const float* __restrict__ Bb, int sB,
                                              float* __restrict__ Cb,
                                              const float* __restrict__ helm,
                                              const float* __restrict__ xin,
                                              float* __restrict__ hout) {
  int s = blockIdx.z;
  const float* A = Ab + (size_t)s * sA;
  const float* B = Bb + (size_t)s * sB;
  int tid = threadIdx.x;
  int tx = tid & 15, ty = tid >> 4;
  int tm0 = blockIdx.y * 64, tn0 = blockIdx.x * 64;
  __shared__ float As[16][68];
  __shared__ float Bs[16][68];
  float c[4][4] = {};
  for (int k0 = 0; k0 < 256; k0 += 16) {
#pragma unroll
    for (int i = 0; i < 4; ++i) {
      int l = tid + i * 256;
      int m = l >> 4, kk = l & 15;
      As[kk][m] = A[(size_t)(tm0 + m) * 256 + k0 + kk];
      int n = l & 63, k2 = l >> 6;
      Bs[k2][n] = B[(size_t)(k0 + k2) * 256 + tn0 + n];
    }
    __syncthreads();
#pragma unroll
    for (int kk = 0; kk < 16; ++kk) {
      float4 av = *(const float4*)&As[kk][ty * 4];
      float4 bv = *(const float4*)&Bs[kk][tx * 4];
      float aa[4] = {av.x, av.y, av.z, av.w};
      float bb[4] = {bv.x, bv.y, bv.z, bv.w};
#pragma unroll
      for (int i = 0; i < 4; ++i)
#pragma unroll
        for (int j = 0; j < 4; ++j) c[i][j] = fmaf(aa[i], bb[j], c[i][j]);
    }
    __syncthreads();
  }
  if (EPI == 0 || EPI == 1) {
    float* C = Cb + (size_t)s * NPIX;
#pragma unroll
    for (int i = 0; i < 4; ++i) {
      int m = tm0 + ty * 4 + i, n = tn0 + tx * 4;
      float4 v = make_float4(c[i][0], c[i][1], c[i][2], c[i][3]);
      if (EPI == 1) {
        float4 hm = *(const float4*)&helm[(size_t)m * 256 + n];
        v.x /= hm.x; v.y /= hm.y; v.z /= hm.z; v.w /= hm.w;
      }
      *(float4*)&C[(size_t)m * 256 + n] = v;
    }
  } else {
    int b = s / 14, t = s - b * 14;
    const float* hb = xin + (size_t)(b * 15 + t) * NPIX;
    float* H = hout + (size_t)s * NPIX;
#pragma unroll
    for (int i = 0; i < 4; ++i) {
      int m = tm0 + ty * 4 + i;
      if (m >= 255) continue;
#pragma unroll
      for (int j = 0; j < 4; ++j) {
        int n = tn0 + tx * 4 + j;
        if (n >= 255) continue;
        size_t o = (size_t)(m + 1) * 256 + (n + 1);
        float hv = c[i][j] + hb[o];
        H[o] = fminf(fmaxf(hv, -HCLAMP), HCLAMP);
      }
    }
  }
}

// ---------------- direct 3x3 SAME conv ----------------
// EMODE 0: out = acc; 1: out = acc * other; 2: out = acc + other
template <int ICU, int OC, int ICW, bool RELU, int EMODE>
__global__ __launch_bounds__(256) void conv3(const float* __restrict__ in,
                                             const float* __restrict__ w,
                                             const float* __restrict__ bias,
                                             const float* __restrict__ other,
                                             float* __restrict__ out, int icw0) {
  const int tx = threadIdx.x & 15, ty = threadIdx.x >> 4;
  const int bx = blockIdx.x, by = blockIdx.y, b = blockIdx.z;
  const int gx = bx * 16 + tx, gy = by * 16 + ty;
  __shared__ float tile[4][18 * 19];
  float acc[OC];
#pragma unroll
  for (int o = 0; o < OC; ++o) acc[o] = bias ? bias[o] : 0.f;
  for (int ic0 = 0; ic0 < ICU; ic0 += 4) {
    const int nc = (ICU - ic0) < 4 ? (ICU - ic0) : 4;
    __syncthreads();
    for (int l = threadIdx.x; l < nc * 324; l += 256) {
      int c = l / 324, rr = l - c * 324;
      int lyy = rr / 18, lxx = rr - lyy * 18;
      int iy = by * 16 + lyy - 1, ix = bx * 16 + lxx - 1;
      float v = 0.f;
      if (iy >= 0 && iy < 256 && ix >= 0 && ix < 256) {
        v = in[(((size_t)b * ICU + ic0 + c) * 256 + iy) * 256 + ix];
        if (RELU) v = fmaxf(v, 0.f);
      }
      tile[c][lyy * 19 + lxx] = v;
    }
    __syncthreads();
    for (int c = 0; c < nc; ++c) {
      const float* tc = tile[c];
      float r0 = tc[ty * 19 + tx], r1 = tc[ty * 19 + tx + 1], r2 = tc[ty * 19 + tx + 2];
      float r3 = tc[(ty + 1) * 19 + tx], r4 = tc[(ty + 1) * 19 + tx + 1], r5 = tc[(ty + 1) * 19 + tx + 2];
      float r6 = tc[(ty + 2) * 19 + tx], r7 = tc[(ty + 2) * 19 + tx + 1], r8 = tc[(ty + 2) * 19 + tx + 2];
      const float* wc = w + (size_t)(icw0 + ic0 + c) * 9;
#pragma unroll
      for (int o = 0; o < OC; ++o) {
        const float* wo = wc + (size_t)o * ICW * 9;
        float a = acc[o];
        a = fmaf(wo[0], r0, a); a = fmaf(wo[1], r1, a); a = fmaf(wo[2], r2, a);
        a = fmaf(wo[3], r3, a); a = fmaf(wo[4], r4, a); a = fmaf(wo[5], r5, a);
        a = fmaf(wo[6], r6, a); a = fmaf(wo[7], r7, a); a = fmaf(wo[8], r8, a);
        acc[o] = a;
      }
    }
  }
#pragma unroll
  for (int o = 0; o < OC; ++o) {
    size_t oi = (((size_t)b * OC + o) * 256 + gy) * 256 + gx;
    float v = acc[o];
    if (EMODE == 1) v *= other[oi];
    if (EMODE == 2) v += other[oi];
    out[oi] = v;
  }
}

// ---------------- reductions ----------------
__global__ __launch_bounds__(256) void k_red_dyn(const float* __restrict__ x,
                                                 const float* __restrict__ h,
                                                 double* __restrict__ part) {
  double sum = 0.0;
  for (int e = blockIdx.x * 256 + threadIdx.x; e < NS * NPIX; e += NB_RED * 256) {
    int s = e >> 16, p = e & 65535;
    int b = s / 14, t = s - b * 14;
    float d = x[(size_t)(b * 15 + t + 1) * NPIX + p] - h[e];
    sum += (double)d * (double)d;
  }
  for (int o = 32; o > 0; o >>= 1) sum += __shfl_down(sum, o);
  __shared__ double sw[4];
  int lane = threadIdx.x & 63, wid = threadIdx.x >> 6;
  if (lane == 0) sw[wid] = sum;
  __syncthreads();
  if (threadIdx.x == 0) part[blockIdx.x] = sw[0] + sw[1] + sw[2] + sw[3];
}

__global__ __launch_bounds__(256) void k_red_ae(const float* __restrict__ x,
                                                const float* __restrict__ xa,
                                                double* __restrict__ part) {
  double sum = 0.0;
  for (int e = blockIdx.x * 256 + threadIdx.x; e < 60 * NPIX; e += NB_RED * 256) {
    float d = x[e] - xa[e];
    sum += (double)d * (double)d;
  }
  for (int o = 32; o > 0; o >>= 1) sum += __shfl_down(sum, o);
  __shared__ double sw[4];
  int lane = threadIdx.x & 63, wid = threadIdx.x >> 6;
  if (lane == 0) sw[wid] = sum;
  __syncthreads();
  if (threadIdx.x == 0) part[NB_RED + blockIdx.x] = sw[0] + sw[1] + sw[2] + sw[3];
}

__global__ __launch_bounds__(256) void k_final(const double* __restrict__ part,
                                               float* __restrict__ out) {
  double s1 = 0.0, s2 = 0.0;
  for (int i = threadIdx.x; i < NB_RED; i += 256) {
    s1 += part[i];
    s2 += part[NB_RED + i];
  }
  for (int o = 32; o > 0; o >>= 1) {
    s1 += __shfl_down(s1, o);
    s2 += __shfl_down(s2, o);
  }
  __shared__ double a1[4], a2[4];
  int lane = threadIdx.x & 63, wid = threadIdx.x >> 6;
  if (lane == 0) { a1[wid] = s1; a2[wid] = s2; }
  __syncthreads();
  if (threadIdx.x == 0) {
    double v = (a1[0] + a1[1] + a1[2] + a1[3]) / (double)(NS * NPIX)
             + (a2[0] + a2[1] + a2[2] + a2[3]) / (double)(60 * NPIX);
    if (!(v == v)) v = 0.0;                       // NaN guard
    if (v > 1.0e30) v = 1.0e30;                   // keep f32-finite
    if (v < -1.0e30) v = -1.0e30;
    out[0] = (float)v;
  }
}

// ---------------- launcher ----------------
extern "C" void kernel_launch(void* const* d_in, const int* in_sizes, int n_in,
                              void* d_out, int out_size, void* d_ws, size_t ws_size,
                              hipStream_t stream) {
  (void)in_sizes; (void)n_in; (void)out_size; (void)ws_size;
  const float* x     = (const float*)d_in[0];
  const float* w_in  = (const float*)d_in[1];
  const float* b_in  = (const float*)d_in[2];
  const float* w_hid = (const float*)d_in[3];
  const float* b_hid = (const float*)d_in[4];
  const float* w_b1  = (const float*)d_in[5];
  const float* b_b1  = (const float*)d_in[6];
  const float* w_b21 = (const float*)d_in[7];
  const float* b_b21 = (const float*)d_in[8];
  const float* w_b22 = (const float*)d_in[9];
  const float* b_b22 = (const float*)d_in[10];
  const float* w_out = (const float*)d_in[11];
  const float* b_out = (const float*)d_in[12];
  float* ws = (float*)d_ws;
  float* out = (float*)d_out;

  // host-side constants, mirroring the numpy float64->float32 path
  double mc = 0.0;
  for (int k = 0; k < 256; ++k) mc += cos((32.0 + 0.05 * k) * D_PI / 180.0);
  mc /= 256.0;
  float DXf = (float)(0.5 * (5550.0 + 5550.0 * mc));
  float dx2 = DXf * DXf;
  float gf  = (float)(9.81 / 1e-4);
  float ngf = (float)(-9.81 / 1e-4);
  float gfc = (float)(9.81 * 1e-4 / (2.7 * 2.7));
  float fdx = 4.0f * DXf;
  float cc  = 1.0f / (6.0f * DXf);
  float dtf = 21600.0f;

  double* part = (double*)d_ws;  // OFF_PART == 0
  float* S  = ws + OFF_S;
  float* HM = ws + OFF_HELM;
  float* h  = ws + OFF_H;
  float* q0 = ws + OFF_Q0;
  float* q1 = ws + OFF_Q1;
  float* qb = ws + OFF_QB;
  float* tA = ws + OFF_TA;
  float* tB = ws + OFF_TB;

  k_dst_init<<<dim3(256), dim3(256), 0, stream>>>(S, HM, dx2);
  k_qg_init<<<dim3(NS * NPIX / 256), dim3(256), 0, stream>>>(x, h, q0, qb, dx2, gf, gfc);

  float* qc = q0;
  float* qn = q1;
  dim3 gg(4, 4, NS);
  for (int step = 0; step < 4; ++step) {
    k_qrhs<<<dim3(NS * NPIX / 256), dim3(256), 0, stream>>>(h, qc, qb, qn, tA,
                                                            ngf, gf, fdx, cc, dtf);
    // tB = qin @ S
    k_gemm<0><<<gg, dim3(256), 0, stream>>>(tA, NPIX, S, 0, tB, nullptr, nullptr, nullptr);
    // tA = (S @ tB) / HELM
    k_gemm<1><<<gg, dim3(256), 0, stream>>>(S, 0, tB, NPIX, tA, HM, nullptr, nullptr);
    // tB = tA @ S
    k_gemm<0><<<gg, dim3(256), 0, stream>>>(tA, NPIX, S, 0, tB, nullptr, nullptr, nullptr);
    // h[interior] = clamp((S @ tB) + hb)
    k_gemm<2><<<gg, dim3(256), 0, stream>>>(S, 0, tB, NPIX, nullptr, nullptr, x, h);
    float* tmp = qc; qc = qn; qn = tmp;
  }
  k_red_dyn<<<dim3(NB_RED), dim3(256), 0, stream>>>(x, h, part);

  float* z1 = ws + OFF_Z1;
  float* z2 = ws + OFF_Z2;
  float* bc = ws + OFF_BUFC;
  float* xa = ws + OFF_XA;
  dim3 cg(16, 16, 4);
  conv3<15, 64, 15, false, 0><<<cg, dim3(256), 0, stream>>>(x, w_in, b_in, nullptr, z1, 0);
  conv3<64, 64, 64, true, 0><<<cg, dim3(256), 0, stream>>>(z1, w_hid, b_hid, nullptr, z2, 0);
  conv3<64, 64, 64, false, 0><<<cg, dim3(256), 0, stream>>>(z2, w_b1, b_b1, nullptr, z1, 0);
  conv3<64, 64, 64, false, 0><<<cg, dim3(256), 0, stream>>>(z2, w_b21, b_b21, nullptr, bc, 0);
  conv3<64, 64, 64, false, 1><<<cg, dim3(256), 0, stream>>>(z2, w_b22, b_b22, bc, bc, 0);
  conv3<64, 15, 128, false, 0><<<cg, dim3(256), 0, stream>>>(z1, w_out, b_out, nullptr, xa, 0);
  conv3<64, 15, 128, false, 2><<<cg, dim3(256), 0, stream>>>(bc, w_out, nullptr, xa, xa, 64);

  k_red_ae<<<dim3(NB_RED), dim3(256), 0, stream>>>(x, xa, part);
  k_final<<<dim3(1), dim3(256), 0, stream>>>(part, out);
}

// Round 3
// 1016.156 us; speedup vs baseline: 4.4679x; 4.4679x over previous
//
#include <hip/hip_runtime.h>
#include <math.h>

#define NS 56        // B*(T-1)
#define NPIX 65536   // 256*256
#define NB_RED 1024

static constexpr double D_PI = 3.14159265358979323846;

typedef __attribute__((ext_vector_type(8))) short short8;
typedef __attribute__((ext_vector_type(4))) float f32x4;

__device__ inline unsigned short f2bf(float f) {
  union { float f; unsigned int u; } v; v.f = f;
  unsigned int r = v.u + 0x7FFFu + ((v.u >> 16) & 1u);
  return (unsigned short)(r >> 16);
}
__device__ inline float bf2f(unsigned short b) {
  union { float f; unsigned int u; } v; v.u = ((unsigned int)b) << 16;
  return v.f;
}

// ---------------- workspace layout (float offsets) ----------------
#define OFF_PART 0                        // 2048 doubles
#define OFF_S    4096                     // 256*256 bf16 = 32768 f
#define OFF_HM   (OFF_S + 32768)          // 65536 f
#define OFF_H    (OFF_HM + 65536)         // 56*65536 f
#define SLC      (NS * NPIX)
#define OFF_Q0   (OFF_H + SLC)
#define OFF_Q1   (OFF_Q0 + SLC)
#define OFF_QB   (OFF_Q1 + SLC)
#define OFF_TA   (OFF_QB + SLC)           // bf16: SLC/2 floats
#define OFF_U    (OFF_TA + SLC / 2)
#define OFF_V    (OFF_U + SLC / 2)
// conv phase reuses QG region (all QG data dead after k_red_dyn)
#define OFF_XP   OFF_H                    // 4*65536*16 bf16 = 2097152 f
#define OFF_Z1   (OFF_XP + 2097152)       // 4*65536*64 bf16 = 8388608 f
#define OFF_Z2   (OFF_Z1 + 8388608)
#define OFF_BC   (OFF_Z2 + 8388608)
#define OFF_XA   (OFF_BC + 8388608)       // 4*65536*16 bf16 = 2097152 f
#define OFF_WT   (OFF_XA + 2097152)       // beyond both regions
#define WT_IN    0
#define WT_HID   (WT_IN + 5120)
#define WT_B1    (WT_HID + 18432)
#define WT_B21   (WT_B1 + 18432)
#define WT_B22   (WT_B21 + 18432)
#define WT_O1    (WT_B22 + 18432)
#define WT_O2    (WT_O1 + 4608)

#define QCLAMP 1.0e12f
#define HCLAMP 1.0e15f

// ---------------- init: DST matrix (bf16) + Helmholtz eigenvalues ----------------
__global__ __launch_bounds__(256) void k_dst_init(unsigned short* __restrict__ S,
                                                  float* __restrict__ HM, float dx2f) {
  int idx = blockIdx.x * 256 + threadIdx.x;
  int i = idx >> 8, j = idx & 255;
  float sv = 0.f, hv = 1.f;
  if (i < 254 && j < 254) {
    double arg = D_PI * (double)((i + 1) * (j + 1)) / 255.0;
    sv = (float)((2.0 / sqrt(510.0)) * sin(arg));
    double la = 2.0 * (cos(D_PI * (double)(i + 1) / 255.0) - 1.0) / (double)dx2f
              + 2.0 * (cos(D_PI * (double)(j + 1) / 255.0) - 1.0) / (double)dx2f;
    hv = (float)((9.81 / 1e-4) * la - 9.81 * 1e-4 / (2.7 * 2.7));
  }
  S[idx] = f2bf(sv);
  HM[idx] = hv;
}

// ---------------- QG init ----------------
__global__ __launch_bounds__(256) void k_qg_init(const float* __restrict__ x,
                                                 float* __restrict__ h,
                                                 float* __restrict__ q,
                                                 float* __restrict__ qb,
                                                 float dx2, float gf, float gfc) {
  int idx = blockIdx.x * 256 + threadIdx.x;
  int s = idx >> 16, p = idx & 65535;
  int y = p >> 8, xx = p & 255;
  int b = s / 14, t = s - b * 14;
  const float* hb = x + (size_t)(b * 15 + t) * NPIX;
  float hc = hb[p];
  float qv;
  if (y >= 2 && y <= 252 && xx >= 2 && xx <= 252) {
    qv = gf * ((hb[p + 256] + hb[p - 256] - 2.f * hc) / dx2
             + (hb[p + 1] + hb[p - 1] - 2.f * hc) / dx2) - gfc * hc;
  } else {
    qv = -gfc * hc;
  }
  h[idx] = hc;
  q[idx] = qv;
  qb[idx] = qv;
}

// ---------------- q1 update + padded bf16 qin ----------------
__global__ __launch_bounds__(256) void k_qrhs(const float* __restrict__ h,
                                              const float* __restrict__ qc,
                                              const float* __restrict__ qb,
                                              float* __restrict__ qn,
                                              unsigned short* __restrict__ tA,
                                              float ngf, float pgf, float fdx,
                                              float cc, float dtf) {
  int idx = blockIdx.x * 256 + threadIdx.x;
  int s = idx >> 16, p = idx & 65535;
  int y = p >> 8, xx = p & 255;
  const float* H = h + (size_t)s * NPIX;
  const float* Q = qc + (size_t)s * NPIX;
  float qv = Q[p];
  float q1 = qv;
  if (y >= 2 && y <= 252 && xx >= 2 && xx <= 252) {
    float hSW = H[p + 255], hS = H[p + 256], hSE = H[p + 257];
    float hNW = H[p - 257], hN = H[p - 256], hNE = H[p - 255];
    float hW = H[p - 1], hE = H[p + 1];
    float uA = ngf * (hSW + hS - hN - hNW) / fdx;
    float uB = ngf * (hS + hSE - hNE - hN) / fdx;
    float vA = pgf * (hE + hNE - hNW - hW) / fdx;
    float vB = pgf * (hSE + hE - hW - hSW) / fdx;
    float uT = 0.5f * (uA + uB);
    float vT = 0.5f * (vA + vB);
    float up = fmaxf(uT, 0.f), um = fminf(uT, 0.f);
    float vp = fmaxf(vT, 0.f), vm = fminf(vT, 0.f);
    float Q0 = qv;
    float QE = Q[p + 1], QW = Q[p - 1], QEE = Q[p + 2], QWW = Q[p - 2];
    float QS = Q[p + 256], QN = Q[p - 256], QSS = Q[p + 512], QNN = Q[p - 512];
    float r = -up * cc * (2.f * QE + 3.f * Q0 - 6.f * QW + QWW)
            + um * cc * (QEE - 6.f * QE + 3.f * Q0 + 2.f * QW)
            - vp * cc * (2.f * QS + 3.f * Q0 - 6.f * QN + QNN)
            + vm * cc * (QSS - 6.f * QS + 3.f * Q0 + 2.f * QN);
    q1 = qv + dtf * r;
    q1 = fminf(fmaxf(q1, -QCLAMP), QCLAMP);
  }
  qn[idx] = q1;
  int wy = (y == 0) ? 254 : ((y == 255) ? 255 : y - 1);
  int wx = (xx == 0) ? 254 : ((xx == 255) ? 255 : xx - 1);
  float val = 0.f;
  if (y >= 1 && y <= 254 && xx >= 1 && xx <= 254) val = q1 - qb[idx];
  tA[(size_t)s * NPIX + wy * 256 + wx] = f2bf(val);
}

// ---------------- MFMA GEMM: C = S @ X^T (256x256, S symmetric bf16) ----------------
// EPI 0: store C bf16. EPI 1: store (C/HM) bf16. EPI 2: h[int] = clamp(C + hb) f32
template <int EPI>
__global__ __launch_bounds__(256) void k_gemm_mfma(const unsigned short* __restrict__ Sm,
                                                   const unsigned short* __restrict__ Xb,
                                                   unsigned short* __restrict__ Cb,
                                                   const float* __restrict__ HM,
                                                   const float* __restrict__ xin,
                                                   float* __restrict__ hout) {
  int s = blockIdx.z;
  const unsigned short* X = Xb + (size_t)s * NPIX;
  int lane = threadIdx.x & 63, wave = threadIdx.x >> 6;
  int cl = lane & 15, kg = lane >> 4;
  int m0 = blockIdx.y * 64 + (wave >> 1) * 32;
  int n0 = blockIdx.x * 64 + (wave & 1) * 32;
  f32x4 acc[2][2];
#pragma unroll
  for (int i = 0; i < 2; ++i)
#pragma unroll
    for (int j = 0; j < 2; ++j) acc[i][j] = (f32x4){0.f, 0.f, 0.f, 0.f};
#pragma unroll
  for (int kc = 0; kc < 256; kc += 32) {
    short8 a[2], b[2];
#pragma unroll
    for (int t = 0; t < 2; ++t) {
      a[t] = *(const short8*)&Sm[(size_t)(m0 + t * 16 + cl) * 256 + kc + kg * 8];
      b[t] = *(const short8*)&X[(size_t)(n0 + t * 16 + cl) * 256 + kc + kg * 8];
    }
#pragma unroll
    for (int i = 0; i < 2; ++i)
#pragma unroll
      for (int j = 0; j < 2; ++j)
        acc[i][j] = __builtin_amdgcn_mfma_f32_16x16x32_bf16(a[i], b[j], acc[i][j], 0, 0, 0);
  }
  if (EPI == 0 || EPI == 1) {
    unsigned short* C = Cb + (size_t)s * NPIX;
#pragma unroll
    for (int i = 0; i < 2; ++i)
#pragma unroll
      for (int j = 0; j < 2; ++j)
#pragma unroll
        for (int r = 0; r < 4; ++r) {
          int gm = m0 + i * 16 + kg * 4 + r;
          int gn = n0 + j * 16 + cl;
          float v = acc[i][j][r];
          if (EPI == 1) v /= HM[(size_t)gm * 256 + gn];
          C[(size_t)gm * 256 + gn] = f2bf(v);
        }
  } else {
    int b = s / 14, t = s - b * 14;
    const float* hb = xin + (size_t)(b * 15 + t) * NPIX;
    float* H = hout + (size_t)s * NPIX;
#pragma unroll
    for (int i = 0; i < 2; ++i)
#pragma unroll
      for (int j = 0; j < 2; ++j)
#pragma unroll
        for (int r = 0; r < 4; ++r) {
          int gm = m0 + i * 16 + kg * 4 + r;
          int gn = n0 + j * 16 + cl;
          if (gm < 254 && gn < 254) {
            size_t o = (size_t)(gm + 1) * 256 + (gn + 1);
            float hv = acc[i][j][r] + hb[o];
            H[o] = fminf(fmaxf(hv, -HCLAMP), HCLAMP);
          }
        }
  }
}

// ---------------- pack x -> NHWC(16) bf16 ----------------
__global__ __launch_bounds__(256) void k_pack_x(const float* __restrict__ x,
                                                unsigned short* __restrict__ xp) {
  int e = blockIdx.x * 256 + threadIdx.x;  // pixel over 4*65536
  int b = e >> 16, p = e & 65535;
  const float* xb = x + (size_t)b * 15 * NPIX + p;
  union { unsigned short u16[16]; uint4 u4[2]; } vv;
#pragma unroll
  for (int c = 0; c < 15; ++c) vv.u16[c] = f2bf(xb[(size_t)c * NPIX]);
  vv.u16[15] = 0;
  uint4* dst = (uint4*)&xp[(size_t)e * 16];
  dst[0] = vv.u4[0];
  dst[1] = vv.u4[1];
}

// ---------------- weight prep: OIHW f32 -> [chunk][kg][oc][8] bf16 ----------------
__global__ __launch_bounds__(256) void k_wprep(const float* __restrict__ src,
                                               unsigned short* __restrict__ dst,
                                               int chunks, int icpShift, int icw, int ic0,
                                               int icReal, int ocw, int ocReal) {
  int e = blockIdx.x * 256 + threadIdx.x;
  int total = chunks * 4 * ocw * 8;
  if (e >= total) return;
  int j = e & 7;
  int oc = (e >> 3) % ocw;
  int ckg = e / (8 * ocw);
  int kg = ckg & 3, c = ckg >> 2;
  int Kidx = c * 32 + kg * 8 + j;
  int tap = Kidx >> icpShift;
  int ic = Kidx & ((1 << icpShift) - 1);
  float v = 0.f;
  if (tap < 9 && ic < icReal && oc < ocReal)
    v = src[((size_t)oc * icw + ic0 + ic) * 9 + tap];
  dst[e] = f2bf(v);
}

// ---------------- MFMA 3x3 SAME conv, NHWC bf16 ----------------
// SPLITOC: 4 waves x 16oc (OCW=64); else waves split pixel rows (OCW=16)
template <int CHUNKS, int ICP, bool SPLITOC, bool RELU, int EMODE>
__global__ __launch_bounds__(256) void k_conv(const unsigned short* __restrict__ in,
                                              const unsigned short* __restrict__ wt,
                                              const float* __restrict__ bias, int ocReal,
                                              const unsigned short* __restrict__ other,
                                              unsigned short* __restrict__ out) {
  constexpr int OCW = SPLITOC ? 64 : 16;
  constexpr int ACCN = SPLITOC ? 16 : 4;
  int lane = threadIdx.x & 63, wave = threadIdx.x >> 6;
  int cl = lane & 15, kg = lane >> 4;
  int b = blockIdx.z;
  int gx0 = blockIdx.x * 16, gy0 = blockIdx.y * 16;
  int ocg = SPLITOC ? wave : 0;
  int pyB = SPLITOC ? 0 : wave * 4;
  int oc = ocg * 16 + cl;

  short8 wf[CHUNKS];
#pragma unroll
  for (int c = 0; c < CHUNKS; ++c)
    wf[c] = *(const short8*)&wt[(((size_t)c * 4 + kg) * OCW + oc) * 8];

  float bv = 0.f;
  if (bias != nullptr && oc < ocReal) bv = bias[oc];
  f32x4 acc[ACCN];
#pragma unroll
  for (int m = 0; m < ACCN; ++m) acc[m] = (f32x4){bv, bv, bv, bv};

  const unsigned short* inb = in + (size_t)b * NPIX * ICP;
  const short8 z8 = {0, 0, 0, 0, 0, 0, 0, 0};

#pragma unroll
  for (int c = 0; c < CHUNKS; ++c) {
    int tap, icoff;
    if (ICP == 64) { tap = c >> 1; icoff = (c & 1) * 32 + kg * 8; }
    else           { tap = 2 * c + (kg >> 1); icoff = (kg & 1) * 8; }
    int dy = tap / 3, dx = tap - dy * 3;   // tap 9 (pad): dy=3,dx=0, weights are 0
    int cx = gx0 + cl + dx - 1;
    bool cok = (cx >= 0) && (cx < 256);
    int cc2 = cx < 0 ? 0 : (cx > 255 ? 255 : cx);
#pragma unroll
    for (int m = 0; m < ACCN; ++m) {
      int py = pyB + m;
      int row = gy0 + py + dy - 1;
      bool ok = cok && (row >= 0) && (row < 256);
      int rc = row < 0 ? 0 : (row > 255 ? 255 : row);
      short8 av = *(const short8*)&inb[((size_t)rc * 256 + cc2) * ICP + icoff];
      av = ok ? av : z8;
      acc[m] = __builtin_amdgcn_mfma_f32_16x16x32_bf16(av, wf[c], acc[m], 0, 0, 0);
    }
  }

  const size_t outBase = (size_t)b * NPIX * OCW;
#pragma unroll
  for (int m = 0; m < ACCN; ++m) {
    int py = pyB + m;
#pragma unroll
    for (int r = 0; r < 4; ++r) {
      int px = kg * 4 + r;
      size_t oi = outBase + ((size_t)(gy0 + py) * 256 + gx0 + px) * OCW + oc;
      float v = acc[m][r];
      if (EMODE == 1) v *= bf2f(other[oi]);
      if (EMODE == 2) v += bf2f(other[oi]);
      if (RELU) v = fmaxf(v, 0.f);
      out[oi] = f2bf(v);
    }
  }
}

// ---------------- reductions ----------------
__global__ __launch_bounds__(256) void k_red_dyn(const float* __restrict__ x,
                                                 const float* __restrict__ h,
                                                 double* __restrict__ part) {
  double sum = 0.0;
  for (int e = blockIdx.x * 256 + threadIdx.x; e < NS * NPIX; e += NB_RED * 256) {
    int s = e >> 16, p = e & 65535;
    int b = s / 14, t = s - b * 14;
    float d = x[(size_t)(b * 15 + t + 1) * NPIX + p] - h[e];
    sum += (double)d * (double)d;
  }
  for (int o = 32; o > 0; o >>= 1) sum += __shfl_down(sum, o);
  __shared__ double sw[4];
  int lane = threadIdx.x & 63, wid = threadIdx.x >> 6;
  if (lane == 0) sw[wid] = sum;
  __syncthreads();
  if (threadIdx.x == 0) part[blockIdx.x] = sw[0] + sw[1] + sw[2] + sw[3];
}

__global__ __launch_bounds__(256) void k_red_ae(const float* __restrict__ x,
                                                const unsigned short* __restrict__ xa,
                                                double* __restrict__ part) {
  double sum = 0.0;
  for (int e = blockIdx.x * 256 + threadIdx.x; e < 60 * NPIX; e += NB_RED * 256) {
    int b = e / (15 * NPIX);
    int r2 = e - b * 15 * NPIX;
    int c = r2 >> 16, p = r2 & 65535;
    float xav = bf2f(xa[((size_t)b * NPIX + p) * 16 + c]);
    float d = x[e] - xav;
    sum += (double)d * (double)d;
  }
  for (int o = 32; o > 0; o >>= 1) sum += __shfl_down(sum, o);
  __shared__ double sw[4];
  int lane = threadIdx.x & 63, wid = threadIdx.x >> 6;
  if (lane == 0) sw[wid] = sum;
  __syncthreads();
  if (threadIdx.x == 0) part[NB_RED + blockIdx.x] = sw[0] + sw[1] + sw[2] + sw[3];
}

__global__ __launch_bounds__(256) void k_final(const double* __restrict__ part,
                                               float* __restrict__ out) {
  double s1 = 0.0, s2 = 0.0;
  for (int i = threadIdx.x; i < NB_RED; i += 256) {
    s1 += part[i];
    s2 += part[NB_RED + i];
  }
  for (int o = 32; o > 0; o >>= 1) {
    s1 += __shfl_down(s1, o);
    s2 += __shfl_down(s2, o);
  }
  __shared__ double a1[4], a2[4];
  int lane = threadIdx.x & 63, wid = threadIdx.x >> 6;
  if (lane == 0) { a1[wid] = s1; a2[wid] = s2; }
  __syncthreads();
  if (threadIdx.x == 0) {
    double v = (a1[0] + a1[1] + a1[2] + a1[3]) / (double)(NS * NPIX)
             + (a2[0] + a2[1] + a2[2] + a2[3]) / (double)(60 * NPIX);
    if (!(v == v)) v = 0.0;
    if (v > 1.0e30) v = 1.0e30;
    if (v < -1.0e30) v = -1.0e30;
    out[0] = (float)v;
  }
}

// ---------------- launcher ----------------
extern "C" void kernel_launch(void* const* d_in, const int* in_sizes, int n_in,
                              void* d_out, int out_size, void* d_ws, size_t ws_size,
                              hipStream_t stream) {
  (void)in_sizes; (void)n_in; (void)out_size; (void)ws_size;
  const float* x     = (const float*)d_in[0];
  const float* w_in  = (const float*)d_in[1];
  const float* b_in  = (const float*)d_in[2];
  const float* w_hid = (const float*)d_in[3];
  const float* b_hid = (const float*)d_in[4];
  const float* w_b1  = (const float*)d_in[5];
  const float* b_b1  = (const float*)d_in[6];
  const float* w_b21 = (const float*)d_in[7];
  const float* b_b21 = (const float*)d_in[8];
  const float* w_b22 = (const float*)d_in[9];
  const float* b_b22 = (const float*)d_in[10];
  const float* w_out = (const float*)d_in[11];
  const float* b_out = (const float*)d_in[12];
  float* ws = (float*)d_ws;
  float* out = (float*)d_out;

  double mc = 0.0;
  for (int k = 0; k < 256; ++k) mc += cos((32.0 + 0.05 * k) * D_PI / 180.0);
  mc /= 256.0;
  float DXf = (float)(0.5 * (5550.0 + 5550.0 * mc));
  float dx2 = DXf * DXf;
  float gf  = (float)(9.81 / 1e-4);
  float ngf = (float)(-9.81 / 1e-4);
  float gfc = (float)(9.81 * 1e-4 / (2.7 * 2.7));
  float fdx = 4.0f * DXf;
  float cc  = 1.0f / (6.0f * DXf);
  float dtf = 21600.0f;

  double* part = (double*)d_ws;
  unsigned short* S  = (unsigned short*)(ws + OFF_S);
  float* HM = ws + OFF_HM;
  float* h  = ws + OFF_H;
  float* q0 = ws + OFF_Q0;
  float* q1 = ws + OFF_Q1;
  float* qb = ws + OFF_QB;
  unsigned short* tA = (unsigned short*)(ws + OFF_TA);
  unsigned short* U  = (unsigned short*)(ws + OFF_U);
  unsigned short* V  = (unsigned short*)(ws + OFF_V);
  unsigned short* wtb = (unsigned short*)(ws + OFF_WT);

  k_dst_init<<<dim3(256), dim3(256), 0, stream>>>(S, HM, dx2);

  // weight prep (src, dst, chunks, icpShift, icw, ic0, icReal, ocw, ocReal)
  k_wprep<<<dim3(40), dim3(256), 0, stream>>>(w_in,  wtb + 2 * WT_IN,  5, 4, 15, 0, 15, 64, 64);
  k_wprep<<<dim3(144), dim3(256), 0, stream>>>(w_hid, wtb + 2 * WT_HID, 18, 6, 64, 0, 64, 64, 64);
  k_wprep<<<dim3(144), dim3(256), 0, stream>>>(w_b1,  wtb + 2 * WT_B1,  18, 6, 64, 0, 64, 64, 64);
  k_wprep<<<dim3(144), dim3(256), 0, stream>>>(w_b21, wtb + 2 * WT_B21, 18, 6, 64, 0, 64, 64, 64);
  k_wprep<<<dim3(144), dim3(256), 0, stream>>>(w_b22, wtb + 2 * WT_B22, 18, 6, 64, 0, 64, 64, 64);
  k_wprep<<<dim3(36), dim3(256), 0, stream>>>(w_out, wtb + 2 * WT_O1, 18, 6, 128, 0, 64, 16, 15);
  k_wprep<<<dim3(36), dim3(256), 0, stream>>>(w_out, wtb + 2 * WT_O2, 18, 6, 128, 64, 64, 16, 15);

  k_qg_init<<<dim3(NS * NPIX / 256), dim3(256), 0, stream>>>(x, h, q0, qb, dx2, gf, gfc);

  float* qc = q0;
  float* qn = q1;
  dim3 gg(4, 4, NS);
  for (int step = 0; step < 4; ++step) {
    k_qrhs<<<dim3(NS * NPIX / 256), dim3(256), 0, stream>>>(h, qc, qb, qn, tA,
                                                            ngf, gf, fdx, cc, dtf);
    k_gemm_mfma<0><<<gg, dim3(256), 0, stream>>>(S, tA, U, nullptr, nullptr, nullptr);
    k_gemm_mfma<1><<<gg, dim3(256), 0, stream>>>(S, U, V, HM, nullptr, nullptr);
    k_gemm_mfma<0><<<gg, dim3(256), 0, stream>>>(S, V, U, nullptr, nullptr, nullptr);
    k_gemm_mfma<2><<<gg, dim3(256), 0, stream>>>(S, U, nullptr, nullptr, x, h);
    float* tmp = qc; qc = qn; qn = tmp;
  }
  k_red_dyn<<<dim3(NB_RED), dim3(256), 0, stream>>>(x, h, part);

  unsigned short* xp = (unsigned short*)(ws + OFF_XP);
  unsigned short* z1 = (unsigned short*)(ws + OFF_Z1);
  unsigned short* z2 = (unsigned short*)(ws + OFF_Z2);
  unsigned short* bc = (unsigned short*)(ws + OFF_BC);
  unsigned short* xa = (unsigned short*)(ws + OFF_XA);

  k_pack_x<<<dim3(4 * NPIX / 256), dim3(256), 0, stream>>>(x, xp);

  dim3 cg(16, 16, 4);
  // conv_in: xp(16) -> z1 (relu on store)
  k_conv<5, 16, true, true, 0><<<cg, dim3(256), 0, stream>>>(xp, wtb + 2 * WT_IN, b_in, 64, nullptr, z1);
  // hid: z1 -> z2
  k_conv<18, 64, true, false, 0><<<cg, dim3(256), 0, stream>>>(z1, wtb + 2 * WT_HID, b_hid, 64, nullptr, z2);
  // b1: z2 -> z1 (reuse)
  k_conv<18, 64, true, false, 0><<<cg, dim3(256), 0, stream>>>(z2, wtb + 2 * WT_B1, b_b1, 64, nullptr, z1);
  // b21: z2 -> bc
  k_conv<18, 64, true, false, 0><<<cg, dim3(256), 0, stream>>>(z2, wtb + 2 * WT_B21, b_b21, 64, nullptr, bc);
  // b22: z2 -> bc (multiply by other=bc)
  k_conv<18, 64, true, false, 1><<<cg, dim3(256), 0, stream>>>(z2, wtb + 2 * WT_B22, b_b22, 64, bc, bc);
  // out pass1: z1 -> xa
  k_conv<18, 64, false, false, 0><<<cg, dim3(256), 0, stream>>>(z1, wtb + 2 * WT_O1, b_out, 15, nullptr, xa);
  // out pass2: bc -> xa (accumulate)
  k_conv<18, 64, false, false, 2><<<cg, dim3(256), 0, stream>>>(bc, wtb + 2 * WT_O2, nullptr, 15, xa, xa);

  k_red_ae<<<dim3(NB_RED), dim3(256), 0, stream>>>(x, xa, part);
  k_final<<<dim3(1), dim3(256), 0, stream>>>(part, out);
}

// Round 4
// 705.807 us; speedup vs baseline: 6.4325x; 1.4397x over previous
//
#include <hip/hip_runtime.h>
#include <math.h>

#define NS 56        // B*(T-1)
#define NPIX 65536   // 256*256
#define NB_RED 1024

static constexpr double D_PI = 3.14159265358979323846;

typedef __attribute__((ext_vector_type(8))) short short8;
typedef __attribute__((ext_vector_type(4))) float f32x4;

__device__ inline unsigned short f2bf(float f) {
  union { float f; unsigned int u; } v; v.f = f;
  unsigned int r = v.u + 0x7FFFu + ((v.u >> 16) & 1u);
  return (unsigned short)(r >> 16);
}
__device__ inline float bf2f(unsigned short b) {
  union { float f; unsigned int u; } v; v.u = ((unsigned int)b) << 16;
  return v.f;
}

// ---------------- workspace layout (float offsets) ----------------
#define OFF_PART 0                        // 2048 doubles
#define OFF_S    4096                     // 256*256 bf16 = 32768 f
#define OFF_HM   (OFF_S + 32768)          // 65536 f
#define OFF_H    (OFF_HM + 65536)         // 56*65536 f
#define SLC      (NS * NPIX)
#define OFF_Q0   (OFF_H + SLC)
#define OFF_Q1   (OFF_Q0 + SLC)
#define OFF_QB   (OFF_Q1 + SLC)
#define OFF_TA   (OFF_QB + SLC)           // bf16: SLC/2 floats
#define OFF_U    (OFF_TA + SLC / 2)
#define OFF_V    (OFF_U + SLC / 2)
// conv phase reuses QG region (all QG data dead after k_red_dyn)
#define OFF_XP   OFF_H                    // 4*65536*16 bf16 = 2097152 f
#define OFF_Z1   (OFF_XP + 2097152)       // 4*65536*64 bf16 = 8388608 f
#define OFF_Z2   (OFF_Z1 + 8388608)
#define OFF_BC   (OFF_Z2 + 8388608)
#define OFF_XA   (OFF_BC + 8388608)       // 4*65536*16 bf16 = 2097152 f
#define OFF_WT   (OFF_XA + 2097152)
#define WT_IN    0
#define WT_HID   (WT_IN + 5120)
#define WT_B1    (WT_HID + 18432)
#define WT_B21   (WT_B1 + 18432)
#define WT_B22   (WT_B21 + 18432)
#define WT_O1    (WT_B22 + 18432)
#define WT_O2    (WT_O1 + 4608)

#define QCLAMP 1.0e12f
#define HCLAMP 1.0e15f

// ---------------- init: DST matrix (bf16) + Helmholtz eigenvalues ----------------
__global__ __launch_bounds__(256) void k_dst_init(unsigned short* __restrict__ S,
                                                  float* __restrict__ HM, float dx2f) {
  int idx = blockIdx.x * 256 + threadIdx.x;
  int i = idx >> 8, j = idx & 255;
  float sv = 0.f, hv = 1.f;
  if (i < 254 && j < 254) {
    double arg = D_PI * (double)((i + 1) * (j + 1)) / 255.0;
    sv = (float)((2.0 / sqrt(510.0)) * sin(arg));
    double la = 2.0 * (cos(D_PI * (double)(i + 1) / 255.0) - 1.0) / (double)dx2f
              + 2.0 * (cos(D_PI * (double)(j + 1) / 255.0) - 1.0) / (double)dx2f;
    hv = (float)((9.81 / 1e-4) * la - 9.81 * 1e-4 / (2.7 * 2.7));
  }
  S[idx] = f2bf(sv);
  HM[idx] = hv;
}

// ---------------- QG init ----------------
__global__ __launch_bounds__(256) void k_qg_init(const float* __restrict__ x,
                                                 float* __restrict__ h,
                                                 float* __restrict__ q,
                                                 float* __restrict__ qb,
                                                 float dx2, float gf, float gfc) {
  int idx = blockIdx.x * 256 + threadIdx.x;
  int s = idx >> 16, p = idx & 65535;
  int y = p >> 8, xx = p & 255;
  int b = s / 14, t = s - b * 14;
  const float* hb = x + (size_t)(b * 15 + t) * NPIX;
  float hc = hb[p];
  float qv;
  if (y >= 2 && y <= 252 && xx >= 2 && xx <= 252) {
    qv = gf * ((hb[p + 256] + hb[p - 256] - 2.f * hc) / dx2
             + (hb[p + 1] + hb[p - 1] - 2.f * hc) / dx2) - gfc * hc;
  } else {
    qv = -gfc * hc;
  }
  h[idx] = hc;
  q[idx] = qv;
  qb[idx] = qv;
}

// ---------------- q1 update + padded bf16 qin ----------------
__global__ __launch_bounds__(256) void k_qrhs(const float* __restrict__ h,
                                              const float* __restrict__ qc,
                                              const float* __restrict__ qb,
                                              float* __restrict__ qn,
                                              unsigned short* __restrict__ tA,
                                              float ngf, float pgf, float fdx,
                                              float cc, float dtf) {
  int idx = blockIdx.x * 256 + threadIdx.x;
  int s = idx >> 16, p = idx & 65535;
  int y = p >> 8, xx = p & 255;
  const float* H = h + (size_t)s * NPIX;
  const float* Q = qc + (size_t)s * NPIX;
  float qv = Q[p];
  float q1 = qv;
  if (y >= 2 && y <= 252 && xx >= 2 && xx <= 252) {
    float hSW = H[p + 255], hS = H[p + 256], hSE = H[p + 257];
    float hNW = H[p - 257], hN = H[p - 256], hNE = H[p - 255];
    float hW = H[p - 1], hE = H[p + 1];
    float uA = ngf * (hSW + hS - hN - hNW) / fdx;
    float uB = ngf * (hS + hSE - hNE - hN) / fdx;
    float vA = pgf * (hE + hNE - hNW - hW) / fdx;
    float vB = pgf * (hSE + hE - hW - hSW) / fdx;
    float uT = 0.5f * (uA + uB);
    float vT = 0.5f * (vA + vB);
    float up = fmaxf(uT, 0.f), um = fminf(uT, 0.f);
    float vp = fmaxf(vT, 0.f), vm = fminf(vT, 0.f);
    float Q0 = qv;
    float QE = Q[p + 1], QW = Q[p - 1], QEE = Q[p + 2], QWW = Q[p - 2];
    float QS = Q[p + 256], QN = Q[p - 256], QSS = Q[p + 512], QNN = Q[p - 512];
    float r = -up * cc * (2.f * QE + 3.f * Q0 - 6.f * QW + QWW)
            + um * cc * (QEE - 6.f * QE + 3.f * Q0 + 2.f * QW)
            - vp * cc * (2.f * QS + 3.f * Q0 - 6.f * QN + QNN)
            + vm * cc * (QSS - 6.f * QS + 3.f * Q0 + 2.f * QN);
    q1 = qv + dtf * r;
    q1 = fminf(fmaxf(q1, -QCLAMP), QCLAMP);
  }
  qn[idx] = q1;
  int wy = (y == 0) ? 254 : ((y == 255) ? 255 : y - 1);
  int wx = (xx == 0) ? 254 : ((xx == 255) ? 255 : xx - 1);
  float val = 0.f;
  if (y >= 1 && y <= 254 && xx >= 1 && xx <= 254) val = q1 - qb[idx];
  tA[(size_t)s * NPIX + wy * 256 + wx] = f2bf(val);
}

// ---------------- MFMA GEMM: C = S @ X^T (256x256, S symmetric bf16) ----------------
template <int EPI>
__global__ __launch_bounds__(256) void k_gemm_mfma(const unsigned short* __restrict__ Sm,
                                                   const unsigned short* __restrict__ Xb,
                                                   unsigned short* __restrict__ Cb,
                                                   const float* __restrict__ HM,
                                                   const float* __restrict__ xin,
                                                   float* __restrict__ hout) {
  int s = blockIdx.z;
  const unsigned short* X = Xb + (size_t)s * NPIX;
  int lane = threadIdx.x & 63, wave = threadIdx.x >> 6;
  int cl = lane & 15, kg = lane >> 4;
  int m0 = blockIdx.y * 64 + (wave >> 1) * 32;
  int n0 = blockIdx.x * 64 + (wave & 1) * 32;
  f32x4 acc[2][2];
#pragma unroll
  for (int i = 0; i < 2; ++i)
#pragma unroll
    for (int j = 0; j < 2; ++j) acc[i][j] = (f32x4){0.f, 0.f, 0.f, 0.f};
#pragma unroll
  for (int kc = 0; kc < 256; kc += 32) {
    short8 a[2], b[2];
#pragma unroll
    for (int t = 0; t < 2; ++t) {
      a[t] = *(const short8*)&Sm[(size_t)(m0 + t * 16 + cl) * 256 + kc + kg * 8];
      b[t] = *(const short8*)&X[(size_t)(n0 + t * 16 + cl) * 256 + kc + kg * 8];
    }
#pragma unroll
    for (int i = 0; i < 2; ++i)
#pragma unroll
      for (int j = 0; j < 2; ++j)
        acc[i][j] = __builtin_amdgcn_mfma_f32_16x16x32_bf16(a[i], b[j], acc[i][j], 0, 0, 0);
  }
  if (EPI == 0 || EPI == 1) {
    unsigned short* C = Cb + (size_t)s * NPIX;
#pragma unroll
    for (int i = 0; i < 2; ++i)
#pragma unroll
      for (int j = 0; j < 2; ++j)
#pragma unroll
        for (int r = 0; r < 4; ++r) {
          int gm = m0 + i * 16 + kg * 4 + r;
          int gn = n0 + j * 16 + cl;
          float v = acc[i][j][r];
          if (EPI == 1) v /= HM[(size_t)gm * 256 + gn];
          C[(size_t)gm * 256 + gn] = f2bf(v);
        }
  } else {
    int b = s / 14, t = s - b * 14;
    const float* hb = xin + (size_t)(b * 15 + t) * NPIX;
    float* H = hout + (size_t)s * NPIX;
#pragma unroll
    for (int i = 0; i < 2; ++i)
#pragma unroll
      for (int j = 0; j < 2; ++j)
#pragma unroll
        for (int r = 0; r < 4; ++r) {
          int gm = m0 + i * 16 + kg * 4 + r;
          int gn = n0 + j * 16 + cl;
          if (gm < 254 && gn < 254) {
            size_t o = (size_t)(gm + 1) * 256 + (gn + 1);
            float hv = acc[i][j][r] + hb[o];
            H[o] = fminf(fmaxf(hv, -HCLAMP), HCLAMP);
          }
        }
  }
}

// ---------------- pack x -> NHWC(16) bf16 ----------------
__global__ __launch_bounds__(256) void k_pack_x(const float* __restrict__ x,
                                                unsigned short* __restrict__ xp) {
  int e = blockIdx.x * 256 + threadIdx.x;
  int b = e >> 16, p = e & 65535;
  const float* xb = x + (size_t)b * 15 * NPIX + p;
  union { unsigned short u16[16]; uint4 u4[2]; } vv;
#pragma unroll
  for (int c = 0; c < 15; ++c) vv.u16[c] = f2bf(xb[(size_t)c * NPIX]);
  vv.u16[15] = 0;
  uint4* dst = (uint4*)&xp[(size_t)e * 16];
  dst[0] = vv.u4[0];
  dst[1] = vv.u4[1];
}

// ---------------- weight prep: OIHW f32 -> [chunk][kg][oc][8] bf16 ----------------
__global__ __launch_bounds__(256) void k_wprep(const float* __restrict__ src,
                                               unsigned short* __restrict__ dst,
                                               int chunks, int icpShift, int icw, int ic0,
                                               int icReal, int ocw, int ocReal) {
  int e = blockIdx.x * 256 + threadIdx.x;
  int total = chunks * 4 * ocw * 8;
  if (e >= total) return;
  int j = e & 7;
  int oc = (e >> 3) % ocw;
  int ckg = e / (8 * ocw);
  int kg = ckg & 3, c = ckg >> 2;
  int Kidx = c * 32 + kg * 8 + j;
  int tap = Kidx >> icpShift;
  int ic = Kidx & ((1 << icpShift) - 1);
  float v = 0.f;
  if (tap < 9 && ic < icReal && oc < ocReal)
    v = src[((size_t)oc * icw + ic0 + ic) * 9 + tap];
  dst[e] = f2bf(v);
}

// ---------------- MFMA 3x3 SAME conv, NHWC bf16, pixel-split waves ----------------
// Block: 16x16 pixels, 4 waves x 4 rows. Wave covers all OCW=NOC*16 out channels.
// Chunks >= 18 switch to (in1, wt1) for dual-source (concat) convs.
// EMODE 0: store acc; 1: store acc * other[oi]
template <int CHUNKS, int ICP, bool RELU, int EMODE, int NOC>
__global__ __launch_bounds__(256) void k_conv(const unsigned short* __restrict__ in0,
                                              const unsigned short* __restrict__ in1,
                                              const unsigned short* __restrict__ wt0,
                                              const unsigned short* __restrict__ wt1,
                                              const float* __restrict__ bias, int ocReal,
                                              const unsigned short* __restrict__ other,
                                              unsigned short* __restrict__ out) {
  constexpr int OCW = NOC * 16;
  int lane = threadIdx.x & 63, wave = threadIdx.x >> 6;
  int cl = lane & 15, kg = lane >> 4;
  int b = blockIdx.z;
  int gx0 = blockIdx.x * 16, gy0 = blockIdx.y * 16;
  int y0 = gy0 + wave * 4;

  f32x4 acc[4][NOC];
#pragma unroll
  for (int j = 0; j < NOC; ++j) {
    int oc = j * 16 + cl;
    float bv = (bias != nullptr && oc < ocReal) ? bias[oc] : 0.f;
#pragma unroll
    for (int i = 0; i < 4; ++i) acc[i][j] = (f32x4){bv, bv, bv, bv};
  }

  const short8 z8 = {0, 0, 0, 0, 0, 0, 0, 0};

#pragma unroll
  for (int c = 0; c < CHUNKS; ++c) {
    const bool second = (CHUNKS > 18) && (c >= 18);
    const unsigned short* inb = second ? in1 : in0;
    const unsigned short* wtb = second ? wt1 : wt0;
    const int cm = second ? (c - 18) : c;
    int tap, icoff;
    if (ICP == 64) { tap = cm >> 1; icoff = (cm & 1) * 32 + kg * 8; }
    else           { tap = 2 * cm + (kg >> 1); icoff = (kg & 1) * 8; }
    int dy = tap / 3, dx = tap - dy * 3;   // tap 9 (pad): weights are zero

    short8 bfr[NOC];
#pragma unroll
    for (int j = 0; j < NOC; ++j)
      bfr[j] = *(const short8*)&wtb[(((size_t)cm * 4 + kg) * OCW + j * 16 + cl) * 8];

    int cx = gx0 + cl + dx - 1;
    bool cok = (cx >= 0) && (cx < 256);
    int cc2 = cx < 0 ? 0 : (cx > 255 ? 255 : cx);
    const unsigned short* inB = inb + (size_t)b * NPIX * ICP;
#pragma unroll
    for (int i = 0; i < 4; ++i) {
      int row = y0 + i + dy - 1;
      bool ok = cok && (row >= 0) && (row < 256);
      int rc = row < 0 ? 0 : (row > 255 ? 255 : row);
      short8 av = *(const short8*)&inB[((size_t)rc * 256 + cc2) * ICP + icoff];
      av = ok ? av : z8;
#pragma unroll
      for (int j = 0; j < NOC; ++j)
        acc[i][j] = __builtin_amdgcn_mfma_f32_16x16x32_bf16(av, bfr[j], acc[i][j], 0, 0, 0);
    }
  }

  const size_t outBase = (size_t)b * NPIX * OCW;
#pragma unroll
  for (int i = 0; i < 4; ++i) {
    int y = y0 + i;
#pragma unroll
    for (int j = 0; j < NOC; ++j) {
      int oc = j * 16 + cl;
#pragma unroll
      for (int r = 0; r < 4; ++r) {
        int px = gx0 + kg * 4 + r;
        size_t oi = outBase + ((size_t)y * 256 + px) * OCW + oc;
        float v = acc[i][j][r];
        if (EMODE == 1) v *= bf2f(other[oi]);
        if (RELU) v = fmaxf(v, 0.f);
        out[oi] = f2bf(v);
      }
    }
  }
}

// ---------------- reductions ----------------
__global__ __launch_bounds__(256) void k_red_dyn(const float* __restrict__ x,
                                                 const float* __restrict__ h,
                                                 double* __restrict__ part) {
  double sum = 0.0;
  for (int e = blockIdx.x * 256 + threadIdx.x; e < NS * NPIX; e += NB_RED * 256) {
    int s = e >> 16, p = e & 65535;
    int b = s / 14, t = s - b * 14;
    float d = x[(size_t)(b * 15 + t + 1) * NPIX + p] - h[e];
    sum += (double)d * (double)d;
  }
  for (int o = 32; o > 0; o >>= 1) sum += __shfl_down(sum, o);
  __shared__ double sw[4];
  int lane = threadIdx.x & 63, wid = threadIdx.x >> 6;
  if (lane == 0) sw[wid] = sum;
  __syncthreads();
  if (threadIdx.x == 0) part[blockIdx.x] = sw[0] + sw[1] + sw[2] + sw[3];
}

__global__ __launch_bounds__(256) void k_red_ae(const float* __restrict__ x,
                                                const unsigned short* __restrict__ xa,
                                                double* __restrict__ part) {
  double sum = 0.0;
  for (int e = blockIdx.x * 256 + threadIdx.x; e < 60 * NPIX; e += NB_RED * 256) {
    int b = e / (15 * NPIX);
    int r2 = e - b * 15 * NPIX;
    int c = r2 >> 16, p = r2 & 65535;
    float xav = bf2f(xa[((size_t)b * NPIX + p) * 16 + c]);
    float d = x[e] - xav;
    sum += (double)d * (double)d;
  }
  for (int o = 32; o > 0; o >>= 1) sum += __shfl_down(sum, o);
  __shared__ double sw[4];
  int lane = threadIdx.x & 63, wid = threadIdx.x >> 6;
  if (lane == 0) sw[wid] = sum;
  __syncthreads();
  if (threadIdx.x == 0) part[NB_RED + blockIdx.x] = sw[0] + sw[1] + sw[2] + sw[3];
}

__global__ __launch_bounds__(256) void k_final(const double* __restrict__ part,
                                               float* __restrict__ out) {
  double s1 = 0.0, s2 = 0.0;
  for (int i = threadIdx.x; i < NB_RED; i += 256) {
    s1 += part[i];
    s2 += part[NB_RED + i];
  }
  for (int o = 32; o > 0; o >>= 1) {
    s1 += __shfl_down(s1, o);
    s2 += __shfl_down(s2, o);
  }
  __shared__ double a1[4], a2[4];
  int lane = threadIdx.x & 63, wid = threadIdx.x >> 6;
  if (lane == 0) { a1[wid] = s1; a2[wid] = s2; }
  __syncthreads();
  if (threadIdx.x == 0) {
    double v = (a1[0] + a1[1] + a1[2] + a1[3]) / (double)(NS * NPIX)
             + (a2[0] + a2[1] + a2[2] + a2[3]) / (double)(60 * NPIX);
    if (!(v == v)) v = 0.0;
    if (v > 1.0e30) v = 1.0e30;
    if (v < -1.0e30) v = -1.0e30;
    out[0] = (float)v;
  }
}

// ---------------- launcher ----------------
extern "C" void kernel_launch(void* const* d_in, const int* in_sizes, int n_in,
                              void* d_out, int out_size, void* d_ws, size_t ws_size,
                              hipStream_t stream) {
  (void)in_sizes; (void)n_in; (void)out_size; (void)ws_size;
  const float* x     = (const float*)d_in[0];
  const float* w_in  = (const float*)d_in[1];
  const float* b_in  = (const float*)d_in[2];
  const float* w_hid = (const float*)d_in[3];
  const float* b_hid = (const float*)d_in[4];
  const float* w_b1  = (const float*)d_in[5];
  const float* b_b1  = (const float*)d_in[6];
  const float* w_b21 = (const float*)d_in[7];
  const float* b_b21 = (const float*)d_in[8];
  const float* w_b22 = (const float*)d_in[9];
  const float* b_b22 = (const float*)d_in[10];
  const float* w_out = (const float*)d_in[11];
  const float* b_out = (const float*)d_in[12];
  float* ws = (float*)d_ws;
  float* out = (float*)d_out;

  double mc = 0.0;
  for (int k = 0; k < 256; ++k) mc += cos((32.0 + 0.05 * k) * D_PI / 180.0);
  mc /= 256.0;
  float DXf = (float)(0.5 * (5550.0 + 5550.0 * mc));
  float dx2 = DXf * DXf;
  float gf  = (float)(9.81 / 1e-4);
  float ngf = (float)(-9.81 / 1e-4);
  float gfc = (float)(9.81 * 1e-4 / (2.7 * 2.7));
  float fdx = 4.0f * DXf;
  float cc  = 1.0f / (6.0f * DXf);
  float dtf = 21600.0f;

  double* part = (double*)d_ws;
  unsigned short* S  = (unsigned short*)(ws + OFF_S);
  float* HM = ws + OFF_HM;
  float* h  = ws + OFF_H;
  float* q0 = ws + OFF_Q0;
  float* q1 = ws + OFF_Q1;
  float* qb = ws + OFF_QB;
  unsigned short* tA = (unsigned short*)(ws + OFF_TA);
  unsigned short* U  = (unsigned short*)(ws + OFF_U);
  unsigned short* V  = (unsigned short*)(ws + OFF_V);
  unsigned short* wtb = (unsigned short*)(ws + OFF_WT);

  k_dst_init<<<dim3(256), dim3(256), 0, stream>>>(S, HM, dx2);

  k_wprep<<<dim3(40), dim3(256), 0, stream>>>(w_in,  wtb + 2 * WT_IN,  5, 4, 15, 0, 15, 64, 64);
  k_wprep<<<dim3(144), dim3(256), 0, stream>>>(w_hid, wtb + 2 * WT_HID, 18, 6, 64, 0, 64, 64, 64);
  k_wprep<<<dim3(144), dim3(256), 0, stream>>>(w_b1,  wtb + 2 * WT_B1,  18, 6, 64, 0, 64, 64, 64);
  k_wprep<<<dim3(144), dim3(256), 0, stream>>>(w_b21, wtb + 2 * WT_B21, 18, 6, 64, 0, 64, 64, 64);
  k_wprep<<<dim3(144), dim3(256), 0, stream>>>(w_b22, wtb + 2 * WT_B22, 18, 6, 64, 0, 64, 64, 64);
  k_wprep<<<dim3(36), dim3(256), 0, stream>>>(w_out, wtb + 2 * WT_O1, 18, 6, 128, 0, 64, 16, 15);
  k_wprep<<<dim3(36), dim3(256), 0, stream>>>(w_out, wtb + 2 * WT_O2, 18, 6, 128, 64, 64, 16, 15);

  k_qg_init<<<dim3(NS * NPIX / 256), dim3(256), 0, stream>>>(x, h, q0, qb, dx2, gf, gfc);

  float* qc = q0;
  float* qn = q1;
  dim3 gg(4, 4, NS);
  for (int step = 0; step < 4; ++step) {
    k_qrhs<<<dim3(NS * NPIX / 256), dim3(256), 0, stream>>>(h, qc, qb, qn, tA,
                                                            ngf, gf, fdx, cc, dtf);
    k_gemm_mfma<0><<<gg, dim3(256), 0, stream>>>(S, tA, U, nullptr, nullptr, nullptr);
    k_gemm_mfma<1><<<gg, dim3(256), 0, stream>>>(S, U, V, HM, nullptr, nullptr);
    k_gemm_mfma<0><<<gg, dim3(256), 0, stream>>>(S, V, U, nullptr, nullptr, nullptr);
    k_gemm_mfma<2><<<gg, dim3(256), 0, stream>>>(S, U, nullptr, nullptr, x, h);
    float* tmp = qc; qc = qn; qn = tmp;
  }
  k_red_dyn<<<dim3(NB_RED), dim3(256), 0, stream>>>(x, h, part);

  unsigned short* xp = (unsigned short*)(ws + OFF_XP);
  unsigned short* z1 = (unsigned short*)(ws + OFF_Z1);
  unsigned short* z2 = (unsigned short*)(ws + OFF_Z2);
  unsigned short* bc = (unsigned short*)(ws + OFF_BC);
  unsigned short* xa = (unsigned short*)(ws + OFF_XA);

  k_pack_x<<<dim3(4 * NPIX / 256), dim3(256), 0, stream>>>(x, xp);

  dim3 cg(16, 16, 4);
  // conv_in: xp(16) -> z1 (relu on store)
  k_conv<5, 16, true, 0, 4><<<cg, dim3(256), 0, stream>>>(
      xp, xp, wtb + 2 * WT_IN, wtb + 2 * WT_IN, b_in, 64, nullptr, z1);
  // hid: z1 -> z2
  k_conv<18, 64, false, 0, 4><<<cg, dim3(256), 0, stream>>>(
      z1, z1, wtb + 2 * WT_HID, wtb + 2 * WT_HID, b_hid, 64, nullptr, z2);
  // b1: z2 -> z1 (reuse)
  k_conv<18, 64, false, 0, 4><<<cg, dim3(256), 0, stream>>>(
      z2, z2, wtb + 2 * WT_B1, wtb + 2 * WT_B1, b_b1, 64, nullptr, z1);
  // b21: z2 -> bc
  k_conv<18, 64, false, 0, 4><<<cg, dim3(256), 0, stream>>>(
      z2, z2, wtb + 2 * WT_B21, wtb + 2 * WT_B21, b_b21, 64, nullptr, bc);
  // b22: z2 -> bc (multiply by other=bc)
  k_conv<18, 64, false, 1, 4><<<cg, dim3(256), 0, stream>>>(
      z2, z2, wtb + 2 * WT_B22, wtb + 2 * WT_B22, b_b22, 64, bc, bc);
  // out: concat(z1, bc) -> xa  (36 chunks, dual source, OC=16)
  k_conv<36, 64, false, 0, 1><<<cg, dim3(256), 0, stream>>>(
      z1, bc, wtb + 2 * WT_O1, wtb + 2 * WT_O2, b_out, 15, nullptr, xa);

  k_red_ae<<<dim3(NB_RED), dim3(256), 0, stream>>>(x, xa, part);
  k_final<<<dim3(1), dim3(256), 0, stream>>>(part, out);
}

// Round 5
// 677.682 us; speedup vs baseline: 6.6994x; 1.0415x over previous
//
#include <hip/hip_runtime.h>
#include <math.h>

#define NS 56        // B*(T-1)
#define NPIX 65536   // 256*256
#define NB_RED 1024

static constexpr double D_PI = 3.14159265358979323846;

typedef __attribute__((ext_vector_type(8))) short short8;
typedef __attribute__((ext_vector_type(4))) float f32x4;

__device__ inline unsigned short f2bf(float f) {
  union { float f; unsigned int u; } v; v.f = f;
  unsigned int r = v.u + 0x7FFFu + ((v.u >> 16) & 1u);
  return (unsigned short)(r >> 16);
}
__device__ inline float bf2f(unsigned short b) {
  union { float f; unsigned int u; } v; v.u = ((unsigned int)b) << 16;
  return v.f;
}

// ---------------- workspace layout (float offsets) ----------------
#define OFF_PART 0                        // 2048 doubles
#define OFF_S    4096                     // 256*256 bf16 = 32768 f
#define OFF_HM   (OFF_S + 32768)          // 65536 f
#define OFF_H    (OFF_HM + 65536)         // 56*65536 f
#define SLC      (NS * NPIX)
#define OFF_Q0   (OFF_H + SLC)
#define OFF_Q1   (OFF_Q0 + SLC)
#define OFF_QB   (OFF_Q1 + SLC)
#define OFF_TA   (OFF_QB + SLC)           // bf16: SLC/2 floats
#define OFF_U    (OFF_TA + SLC / 2)
#define OFF_V    (OFF_U + SLC / 2)
// conv phase reuses QG region (all QG data dead after k_red_dyn)
#define OFF_XP   OFF_H                    // 4*65536*16 bf16 = 2097152 f
#define OFF_Z1   (OFF_XP + 2097152)       // 4*65536*64 bf16 = 8388608 f
#define OFF_Z2   (OFF_Z1 + 8388608)
#define OFF_BC   (OFF_Z2 + 8388608)
#define OFF_XA   (OFF_BC + 8388608)       // 4*65536*16 bf16 = 2097152 f
#define OFF_WT   (OFF_XA + 2097152)
#define WT_IN    0
#define WT_HID   (WT_IN + 5120)
#define WT_B1    (WT_HID + 18432)
#define WT_B21   (WT_B1 + 18432)
#define WT_B22   (WT_B21 + 18432)
#define WT_O1    (WT_B22 + 18432)
#define WT_O2    (WT_O1 + 4608)

#define QCLAMP 1.0e12f
#define HCLAMP 1.0e15f

// ---------------- init: DST matrix (bf16) + Helmholtz eigenvalues ----------------
__global__ __launch_bounds__(256) void k_dst_init(unsigned short* __restrict__ S,
                                                  float* __restrict__ HM, float dx2f) {
  int idx = blockIdx.x * 256 + threadIdx.x;
  int i = idx >> 8, j = idx & 255;
  float sv = 0.f, hv = 1.f;
  if (i < 254 && j < 254) {
    double arg = D_PI * (double)((i + 1) * (j + 1)) / 255.0;
    sv = (float)((2.0 / sqrt(510.0)) * sin(arg));
    double la = 2.0 * (cos(D_PI * (double)(i + 1) / 255.0) - 1.0) / (double)dx2f
              + 2.0 * (cos(D_PI * (double)(j + 1) / 255.0) - 1.0) / (double)dx2f;
    hv = (float)((9.81 / 1e-4) * la - 9.81 * 1e-4 / (2.7 * 2.7));
  }
  S[idx] = f2bf(sv);
  HM[idx] = hv;
}

// ---------------- QG init ----------------
__global__ __launch_bounds__(256) void k_qg_init(const float* __restrict__ x,
                                                 float* __restrict__ h,
                                                 float* __restrict__ q,
                                                 float* __restrict__ qb,
                                                 float dx2, float gf, float gfc) {
  int idx = blockIdx.x * 256 + threadIdx.x;
  int s = idx >> 16, p = idx & 65535;
  int y = p >> 8, xx = p & 255;
  int b = s / 14, t = s - b * 14;
  const float* hb = x + (size_t)(b * 15 + t) * NPIX;
  float hc = hb[p];
  float qv;
  if (y >= 2 && y <= 252 && xx >= 2 && xx <= 252) {
    qv = gf * ((hb[p + 256] + hb[p - 256] - 2.f * hc) / dx2
             + (hb[p + 1] + hb[p - 1] - 2.f * hc) / dx2) - gfc * hc;
  } else {
    qv = -gfc * hc;
  }
  h[idx] = hc;
  q[idx] = qv;
  qb[idx] = qv;
}

// ---------------- q1 update + padded bf16 qin ----------------
__global__ __launch_bounds__(256) void k_qrhs(const float* __restrict__ h,
                                              const float* __restrict__ qc,
                                              const float* __restrict__ qb,
                                              float* __restrict__ qn,
                                              unsigned short* __restrict__ tA,
                                              float ngf, float pgf, float fdx,
                                              float cc, float dtf) {
  int idx = blockIdx.x * 256 + threadIdx.x;
  int s = idx >> 16, p = idx & 65535;
  int y = p >> 8, xx = p & 255;
  const float* H = h + (size_t)s * NPIX;
  const float* Q = qc + (size_t)s * NPIX;
  float qv = Q[p];
  float q1 = qv;
  if (y >= 2 && y <= 252 && xx >= 2 && xx <= 252) {
    float hSW = H[p + 255], hS = H[p + 256], hSE = H[p + 257];
    float hNW = H[p - 257], hN = H[p - 256], hNE = H[p - 255];
    float hW = H[p - 1], hE = H[p + 1];
    float uA = ngf * (hSW + hS - hN - hNW) / fdx;
    float uB = ngf * (hS + hSE - hNE - hN) / fdx;
    float vA = pgf * (hE + hNE - hNW - hW) / fdx;
    float vB = pgf * (hSE + hE - hW - hSW) / fdx;
    float uT = 0.5f * (uA + uB);
    float vT = 0.5f * (vA + vB);
    float up = fmaxf(uT, 0.f), um = fminf(uT, 0.f);
    float vp = fmaxf(vT, 0.f), vm = fminf(vT, 0.f);
    float Q0 = qv;
    float QE = Q[p + 1], QW = Q[p - 1], QEE = Q[p + 2], QWW = Q[p - 2];
    float QS = Q[p + 256], QN = Q[p - 256], QSS = Q[p + 512], QNN = Q[p - 512];
    float r = -up * cc * (2.f * QE + 3.f * Q0 - 6.f * QW + QWW)
            + um * cc * (QEE - 6.f * QE + 3.f * Q0 + 2.f * QW)
            - vp * cc * (2.f * QS + 3.f * Q0 - 6.f * QN + QNN)
            + vm * cc * (QSS - 6.f * QS + 3.f * Q0 + 2.f * QN);
    q1 = qv + dtf * r;
    q1 = fminf(fmaxf(q1, -QCLAMP), QCLAMP);
  }
  qn[idx] = q1;
  int wy = (y == 0) ? 254 : ((y == 255) ? 255 : y - 1);
  int wx = (xx == 0) ? 254 : ((xx == 255) ? 255 : xx - 1);
  float val = 0.f;
  if (y >= 1 && y <= 254 && xx >= 1 && xx <= 254) val = q1 - qb[idx];
  tA[(size_t)s * NPIX + wy * 256 + wx] = f2bf(val);
}

// ---------------- MFMA GEMM: C = S @ X^T (256x256, S symmetric bf16) ----------------
template <int EPI>
__global__ __launch_bounds__(256) void k_gemm_mfma(const unsigned short* __restrict__ Sm,
                                                   const unsigned short* __restrict__ Xb,
                                                   unsigned short* __restrict__ Cb,
                                                   const float* __restrict__ HM,
                                                   const float* __restrict__ xin,
                                                   float* __restrict__ hout) {
  int s = blockIdx.z;
  const unsigned short* X = Xb + (size_t)s * NPIX;
  int lane = threadIdx.x & 63, wave = threadIdx.x >> 6;
  int cl = lane & 15, kg = lane >> 4;
  int m0 = blockIdx.y * 64 + (wave >> 1) * 32;
  int n0 = blockIdx.x * 64 + (wave & 1) * 32;
  f32x4 acc[2][2];
#pragma unroll
  for (int i = 0; i < 2; ++i)
#pragma unroll
    for (int j = 0; j < 2; ++j) acc[i][j] = (f32x4){0.f, 0.f, 0.f, 0.f};
#pragma unroll
  for (int kc = 0; kc < 256; kc += 32) {
    short8 a[2], b[2];
#pragma unroll
    for (int t = 0; t < 2; ++t) {
      a[t] = *(const short8*)&Sm[(size_t)(m0 + t * 16 + cl) * 256 + kc + kg * 8];
      b[t] = *(const short8*)&X[(size_t)(n0 + t * 16 + cl) * 256 + kc + kg * 8];
    }
#pragma unroll
    for (int i = 0; i < 2; ++i)
#pragma unroll
      for (int j = 0; j < 2; ++j)
        acc[i][j] = __builtin_amdgcn_mfma_f32_16x16x32_bf16(a[i], b[j], acc[i][j], 0, 0, 0);
  }
  if (EPI == 0 || EPI == 1) {
    unsigned short* C = Cb + (size_t)s * NPIX;
#pragma unroll
    for (int i = 0; i < 2; ++i)
#pragma unroll
      for (int j = 0; j < 2; ++j)
#pragma unroll
        for (int r = 0; r < 4; ++r) {
          int gm = m0 + i * 16 + kg * 4 + r;
          int gn = n0 + j * 16 + cl;
          float v = acc[i][j][r];
          if (EPI == 1) v /= HM[(size_t)gm * 256 + gn];
          C[(size_t)gm * 256 + gn] = f2bf(v);
        }
  } else {
    int b = s / 14, t = s - b * 14;
    const float* hb = xin + (size_t)(b * 15 + t) * NPIX;
    float* H = hout + (size_t)s * NPIX;
#pragma unroll
    for (int i = 0; i < 2; ++i)
#pragma unroll
      for (int j = 0; j < 2; ++j)
#pragma unroll
        for (int r = 0; r < 4; ++r) {
          int gm = m0 + i * 16 + kg * 4 + r;
          int gn = n0 + j * 16 + cl;
          if (gm < 254 && gn < 254) {
            size_t o = (size_t)(gm + 1) * 256 + (gn + 1);
            float hv = acc[i][j][r] + hb[o];
            H[o] = fminf(fmaxf(hv, -HCLAMP), HCLAMP);
          }
        }
  }
}

// ---------------- pack x -> NHWC(16) bf16 ----------------
__global__ __launch_bounds__(256) void k_pack_x(const float* __restrict__ x,
                                                unsigned short* __restrict__ xp) {
  int e = blockIdx.x * 256 + threadIdx.x;
  int b = e >> 16, p = e & 65535;
  const float* xb = x + (size_t)b * 15 * NPIX + p;
  union { unsigned short u16[16]; uint4 u4[2]; } vv;
#pragma unroll
  for (int c = 0; c < 15; ++c) vv.u16[c] = f2bf(xb[(size_t)c * NPIX]);
  vv.u16[15] = 0;
  uint4* dst = (uint4*)&xp[(size_t)e * 16];
  dst[0] = vv.u4[0];
  dst[1] = vv.u4[1];
}

// ---------------- weight prep: OIHW f32 -> [chunk][kg][oc][8] bf16 ----------------
__global__ __launch_bounds__(256) void k_wprep(const float* __restrict__ src,
                                               unsigned short* __restrict__ dst,
                                               int chunks, int icpShift, int icw, int ic0,
                                               int icReal, int ocw, int ocReal) {
  int e = blockIdx.x * 256 + threadIdx.x;
  int total = chunks * 4 * ocw * 8;
  if (e >= total) return;
  int j = e & 7;
  int oc = (e >> 3) % ocw;
  int ckg = e / (8 * ocw);
  int kg = ckg & 3, c = ckg >> 2;
  int Kidx = c * 32 + kg * 8 + j;
  int tap = Kidx >> icpShift;
  int ic = Kidx & ((1 << icpShift) - 1);
  float v = 0.f;
  if (tap < 9 && ic < icReal && oc < ocReal)
    v = src[((size_t)oc * icw + ic0 + ic) * 9 + tap];
  dst[e] = f2bf(v);
}

// ---------------- MFMA 3x3 SAME conv, NHWC bf16, LDS-staged input tile ----------------
// Block: 16x16 pixels, 4 waves x 4 rows; wave covers OCW=NOC*16 out channels.
// Input tile (18x18 pixels x ICP ch, zero-filled halo) staged in LDS with XOR
// swizzle (slot = group ^ (pixel & (G-1))) -> conflict-free b128 reads, and the
// inner loop has NO bounds checks. DUAL: two sources staged sequentially
// (concat conv); acc carries across both passes.
// EMODE 0: store acc; 1: store acc * other[oi]
template <int CHUNKS, int ICP, bool RELU, int EMODE, int NOC, bool DUAL>
__global__ __launch_bounds__(256) void k_conv(const unsigned short* __restrict__ in0,
                                              const unsigned short* __restrict__ in1,
                                              const unsigned short* __restrict__ wt0,
                                              const unsigned short* __restrict__ wt1,
                                              const float* __restrict__ bias, int ocReal,
                                              const unsigned short* __restrict__ other,
                                              unsigned short* __restrict__ out) {
  constexpr int OCW = NOC * 16;
  constexpr int G = ICP / 8;               // 16B groups per pixel
  constexpr int NPASS = DUAL ? 2 : 1;
  constexpr int CPP = DUAL ? 18 : CHUNKS;  // chunks per pass
  __shared__ unsigned short tile[324 * ICP];

  const int tid = threadIdx.x;
  const int lane = tid & 63, wave = tid >> 6;
  const int cl = lane & 15, kg = lane >> 4;
  const int b = blockIdx.z;
  const int gx0 = blockIdx.x * 16, gy0 = blockIdx.y * 16;

  f32x4 acc[4][NOC];
#pragma unroll
  for (int j = 0; j < NOC; ++j) {
    int oc = j * 16 + cl;
    float bv = (bias != nullptr && oc < ocReal) ? bias[oc] : 0.f;
#pragma unroll
    for (int i = 0; i < 4; ++i) acc[i][j] = (f32x4){bv, bv, bv, bv};
  }

  for (int pass = 0; pass < NPASS; ++pass) {
    const unsigned short* inb = (pass ? in1 : in0) + (size_t)b * NPIX * ICP;
    const unsigned short* wtb = pass ? wt1 : wt0;
    if (pass) __syncthreads();  // all reads of previous tile done
    // ---- stage 18x18 tile, zero halo, swizzled ----
    for (int c = tid; c < 324 * G; c += 256) {
      int pp = c / G, g = c & (G - 1);
      int ly = pp / 18, lx = pp - ly * 18;
      int iy = gy0 + ly - 1, ix = gx0 + lx - 1;
      uint4 v = make_uint4(0u, 0u, 0u, 0u);
      if (iy >= 0 && iy < 256 && ix >= 0 && ix < 256)
        v = *(const uint4*)&inb[((size_t)iy * 256 + ix) * ICP + g * 8];
      int sw = g ^ (pp & (G - 1));
      *(uint4*)&tile[pp * ICP + sw * 8] = v;
    }
    __syncthreads();
    // ---- compute ----
#pragma unroll
    for (int cm = 0; cm < CPP; ++cm) {
      int tap, gidx;
      if (ICP == 64) { tap = cm >> 1; gidx = (cm & 1) * 4 + kg; }
      else           { tap = 2 * cm + (kg >> 1); gidx = kg & 1; }
      int dy = tap / 3, dx = tap - dy * 3;  // tap 9: weights are zero
      short8 bfr[NOC];
#pragma unroll
      for (int j = 0; j < NOC; ++j)
        bfr[j] = *(const short8*)&wtb[(((size_t)cm * 4 + kg) * OCW + j * 16 + cl) * 8];
      int tc = cl + dx;
#pragma unroll
      for (int i = 0; i < 4; ++i) {
        int tr = wave * 4 + i + dy;
        if (tr > 17) tr = 17;               // tap 9 only; zero weights kill it
        int pp = tr * 18 + tc;
        int g2 = gidx ^ (pp & (G - 1));
        short8 av = *(const short8*)&tile[pp * ICP + g2 * 8];
#pragma unroll
        for (int j = 0; j < NOC; ++j)
          acc[i][j] = __builtin_amdgcn_mfma_f32_16x16x32_bf16(av, bfr[j], acc[i][j], 0, 0, 0);
      }
    }
  }

  const size_t outBase = (size_t)b * NPIX * OCW;
#pragma unroll
  for (int i = 0; i < 4; ++i) {
    int y = gy0 + wave * 4 + i;
#pragma unroll
    for (int j = 0; j < NOC; ++j) {
      int oc = j * 16 + cl;
#pragma unroll
      for (int r = 0; r < 4; ++r) {
        int px = gx0 + kg * 4 + r;
        size_t oi = outBase + ((size_t)y * 256 + px) * OCW + oc;
        float v = acc[i][j][r];
        if (EMODE == 1) v *= bf2f(other[oi]);
        if (RELU) v = fmaxf(v, 0.f);
        out[oi] = f2bf(v);
      }
    }
  }
}

// ---------------- reductions ----------------
__global__ __launch_bounds__(256) void k_red_dyn(const float* __restrict__ x,
                                                 const float* __restrict__ h,
                                                 double* __restrict__ part) {
  double sum = 0.0;
  for (int e = blockIdx.x * 256 + threadIdx.x; e < NS * NPIX; e += NB_RED * 256) {
    int s = e >> 16, p = e & 65535;
    int b = s / 14, t = s - b * 14;
    float d = x[(size_t)(b * 15 + t + 1) * NPIX + p] - h[e];
    sum += (double)d * (double)d;
  }
  for (int o = 32; o > 0; o >>= 1) sum += __shfl_down(sum, o);
  __shared__ double sw[4];
  int lane = threadIdx.x & 63, wid = threadIdx.x >> 6;
  if (lane == 0) sw[wid] = sum;
  __syncthreads();
  if (threadIdx.x == 0) part[blockIdx.x] = sw[0] + sw[1] + sw[2] + sw[3];
}

__global__ __launch_bounds__(256) void k_red_ae(const float* __restrict__ x,
                                                const unsigned short* __restrict__ xa,
                                                double* __restrict__ part) {
  double sum = 0.0;
  for (int e = blockIdx.x * 256 + threadIdx.x; e < 60 * NPIX; e += NB_RED * 256) {
    int b = e / (15 * NPIX);
    int r2 = e - b * 15 * NPIX;
    int c = r2 >> 16, p = r2 & 65535;
    float xav = bf2f(xa[((size_t)b * NPIX + p) * 16 + c]);
    float d = x[e] - xav;
    sum += (double)d * (double)d;
  }
  for (int o = 32; o > 0; o >>= 1) sum += __shfl_down(sum, o);
  __shared__ double sw[4];
  int lane = threadIdx.x & 63, wid = threadIdx.x >> 6;
  if (lane == 0) sw[wid] = sum;
  __syncthreads();
  if (threadIdx.x == 0) part[NB_RED + blockIdx.x] = sw[0] + sw[1] + sw[2] + sw[3];
}

__global__ __launch_bounds__(256) void k_final(const double* __restrict__ part,
                                               float* __restrict__ out) {
  double s1 = 0.0, s2 = 0.0;
  for (int i = threadIdx.x; i < NB_RED; i += 256) {
    s1 += part[i];
    s2 += part[NB_RED + i];
  }
  for (int o = 32; o > 0; o >>= 1) {
    s1 += __shfl_down(s1, o);
    s2 += __shfl_down(s2, o);
  }
  __shared__ double a1[4], a2[4];
  int lane = threadIdx.x & 63, wid = threadIdx.x >> 6;
  if (lane == 0) { a1[wid] = s1; a2[wid] = s2; }
  __syncthreads();
  if (threadIdx.x == 0) {
    double v = (a1[0] + a1[1] + a1[2] + a1[3]) / (double)(NS * NPIX)
             + (a2[0] + a2[1] + a2[2] + a2[3]) / (double)(60 * NPIX);
    if (!(v == v)) v = 0.0;
    if (v > 1.0e30) v = 1.0e30;
    if (v < -1.0e30) v = -1.0e30;
    out[0] = (float)v;
  }
}

// ---------------- launcher ----------------
extern "C" void kernel_launch(void* const* d_in, const int* in_sizes, int n_in,
                              void* d_out, int out_size, void* d_ws, size_t ws_size,
                              hipStream_t stream) {
  (void)in_sizes; (void)n_in; (void)out_size; (void)ws_size;
  const float* x     = (const float*)d_in[0];
  const float* w_in  = (const float*)d_in[1];
  const float* b_in  = (const float*)d_in[2];
  const float* w_hid = (const float*)d_in[3];
  const float* b_hid = (const float*)d_in[4];
  const float* w_b1  = (const float*)d_in[5];
  const float* b_b1  = (const float*)d_in[6];
  const float* w_b21 = (const float*)d_in[7];
  const float* b_b21 = (const float*)d_in[8];
  const float* w_b22 = (const float*)d_in[9];
  const float* b_b22 = (const float*)d_in[10];
  const float* w_out = (const float*)d_in[11];
  const float* b_out = (const float*)d_in[12];
  float* ws = (float*)d_ws;
  float* out = (float*)d_out;

  double mc = 0.0;
  for (int k = 0; k < 256; ++k) mc += cos((32.0 + 0.05 * k) * D_PI / 180.0);
  mc /= 256.0;
  float DXf = (float)(0.5 * (5550.0 + 5550.0 * mc));
  float dx2 = DXf * DXf;
  float gf  = (float)(9.81 / 1e-4);
  float ngf = (float)(-9.81 / 1e-4);
  float gfc = (float)(9.81 * 1e-4 / (2.7 * 2.7));
  float fdx = 4.0f * DXf;
  float cc  = 1.0f / (6.0f * DXf);
  float dtf = 21600.0f;

  double* part = (double*)d_ws;
  unsigned short* S  = (unsigned short*)(ws + OFF_S);
  float* HM = ws + OFF_HM;
  float* h  = ws + OFF_H;
  float* q0 = ws + OFF_Q0;
  float* q1 = ws + OFF_Q1;
  float* qb = ws + OFF_QB;
  unsigned short* tA = (unsigned short*)(ws + OFF_TA);
  unsigned short* U  = (unsigned short*)(ws + OFF_U);
  unsigned short* V  = (unsigned short*)(ws + OFF_V);
  unsigned short* wtb = (unsigned short*)(ws + OFF_WT);

  k_dst_init<<<dim3(256), dim3(256), 0, stream>>>(S, HM, dx2);

  k_wprep<<<dim3(40), dim3(256), 0, stream>>>(w_in,  wtb + 2 * WT_IN,  5, 4, 15, 0, 15, 64, 64);
  k_wprep<<<dim3(144), dim3(256), 0, stream>>>(w_hid, wtb + 2 * WT_HID, 18, 6, 64, 0, 64, 64, 64);
  k_wprep<<<dim3(144), dim3(256), 0, stream>>>(w_b1,  wtb + 2 * WT_B1,  18, 6, 64, 0, 64, 64, 64);
  k_wprep<<<dim3(144), dim3(256), 0, stream>>>(w_b21, wtb + 2 * WT_B21, 18, 6, 64, 0, 64, 64, 64);
  k_wprep<<<dim3(144), dim3(256), 0, stream>>>(w_b22, wtb + 2 * WT_B22, 18, 6, 64, 0, 64, 64, 64);
  k_wprep<<<dim3(36), dim3(256), 0, stream>>>(w_out, wtb + 2 * WT_O1, 18, 6, 128, 0, 64, 16, 15);
  k_wprep<<<dim3(36), dim3(256), 0, stream>>>(w_out, wtb + 2 * WT_O2, 18, 6, 128, 64, 64, 16, 15);

  k_qg_init<<<dim3(NS * NPIX / 256), dim3(256), 0, stream>>>(x, h, q0, qb, dx2, gf, gfc);

  float* qc = q0;
  float* qn = q1;
  dim3 gg(4, 4, NS);
  for (int step = 0; step < 4; ++step) {
    k_qrhs<<<dim3(NS * NPIX / 256), dim3(256), 0, stream>>>(h, qc, qb, qn, tA,
                                                            ngf, gf, fdx, cc, dtf);
    k_gemm_mfma<0><<<gg, dim3(256), 0, stream>>>(S, tA, U, nullptr, nullptr, nullptr);
    k_gemm_mfma<1><<<gg, dim3(256), 0, stream>>>(S, U, V, HM, nullptr, nullptr);
    k_gemm_mfma<0><<<gg, dim3(256), 0, stream>>>(S, V, U, nullptr, nullptr, nullptr);
    k_gemm_mfma<2><<<gg, dim3(256), 0, stream>>>(S, U, nullptr, nullptr, x, h);
    float* tmp = qc; qc = qn; qn = tmp;
  }
  k_red_dyn<<<dim3(NB_RED), dim3(256), 0, stream>>>(x, h, part);

  unsigned short* xp = (unsigned short*)(ws + OFF_XP);
  unsigned short* z1 = (unsigned short*)(ws + OFF_Z1);
  unsigned short* z2 = (unsigned short*)(ws + OFF_Z2);
  unsigned short* bc = (unsigned short*)(ws + OFF_BC);
  unsigned short* xa = (unsigned short*)(ws + OFF_XA);

  k_pack_x<<<dim3(4 * NPIX / 256), dim3(256), 0, stream>>>(x, xp);

  dim3 cg(16, 16, 4);
  // conv_in: xp(16) -> z1 (relu on store)
  k_conv<5, 16, true, 0, 4, false><<<cg, dim3(256), 0, stream>>>(
      xp, xp, wtb + 2 * WT_IN, wtb + 2 * WT_IN, b_in, 64, nullptr, z1);
  // hid: z1 -> z2
  k_conv<18, 64, false, 0, 4, false><<<cg, dim3(256), 0, stream>>>(
      z1, z1, wtb + 2 * WT_HID, wtb + 2 * WT_HID, b_hid, 64, nullptr, z2);
  // b1: z2 -> z1 (reuse)
  k_conv<18, 64, false, 0, 4, false><<<cg, dim3(256), 0, stream>>>(
      z2, z2, wtb + 2 * WT_B1, wtb + 2 * WT_B1, b_b1, 64, nullptr, z1);
  // b21: z2 -> bc
  k_conv<18, 64, false, 0, 4, false><<<cg, dim3(256), 0, stream>>>(
      z2, z2, wtb + 2 * WT_B21, wtb + 2 * WT_B21, b_b21, 64, nullptr, bc);
  // b22: z2 -> bc (multiply by other=bc)
  k_conv<18, 64, false, 1, 4, false><<<cg, dim3(256), 0, stream>>>(
      z2, z2, wtb + 2 * WT_B22, wtb + 2 * WT_B22, b_b22, 64, bc, bc);
  // out: concat(z1, bc) -> xa  (dual source, OC=16)
  k_conv<36, 64, false, 0, 1, true><<<cg, dim3(256), 0, stream>>>(
      z1, bc, wtb + 2 * WT_O1, wtb + 2 * WT_O2, b_out, 15, nullptr, xa);

  k_red_ae<<<dim3(NB_RED), dim3(256), 0, stream>>>(x, xa, part);
  k_final<<<dim3(1), dim3(256), 0, stream>>>(part, out);
}